// Round 2
// baseline (1130.464 us; speedup 1.0000x reference)
//
#include <hip/hip_runtime.h>
#include <math.h>

// CNN_tcn, fused d-split: one block per sample (grid 256), 1024 threads =
// 2 threads per row a; thread (a,h) owns d in [32h, 32h+32).
// Unlike round 1, y2/y3 stats are FUSED into the production passes (rolling
// window of just-produced values) -- no extra full-tensor re-read passes.
// The 4 seam rows per thread that need partner values are deferred and fixed
// up from LDS halos after a sync. c2w is staged in LDS transposed [d][o][co]
// so the t16 accumulation does 16 ds_read_b128 broadcasts per iter instead of
// 64 scalar global loads.
// Workspace: ONE [B][D][A] float4 buffer (128 MiB), base2 -> base3 in place;
// all global RAW is same-thread, partner data only via LDS halos.

#define EPS_LN 1e-5f
typedef float4 f4;

__device__ __forceinline__ float gelu_f(float v) {
    return 0.5f * v * (1.0f + erff(v * 0.70710678118654752440f));
}

// y[o] = dilated conv taps: a = base[d-2], c = base[d], e = base[d+2]
// wd layout (4,4,1,3): [o][cin][k] flat o*12 + cin*3 + k
__device__ __forceinline__ void conv4(const f4 a, const f4 c, const f4 e,
                                      const float* __restrict__ wd, float y[4]) {
#pragma unroll
    for (int o = 0; o < 4; ++o) {
        const float* wv = wd + o * 12;
        y[o] = fmaf(a.x, wv[0], fmaf(c.x, wv[1], fmaf(e.x, wv[2],
               fmaf(a.y, wv[3], fmaf(c.y, wv[4], fmaf(e.y, wv[5],
               fmaf(a.z, wv[6], fmaf(c.z, wv[7], fmaf(e.z, wv[8],
               fmaf(a.w, wv[9], fmaf(c.w, wv[10], e.w * wv[11])))))))))));
    }
}

__device__ __forceinline__ void acc_stats(const float y[4], float& s1, float& s2) {
#pragma unroll
    for (int o = 0; o < 4; ++o) { s1 += y[o]; s2 = fmaf(y[o], y[o], s2); }
}

// block-wide reduce of (a,b2) over 1024 threads (16 waves)
__device__ __forceinline__ void block_red2(float& a, float& b2, float* red,
                                           float* bc, int tid) {
#pragma unroll
    for (int off = 32; off > 0; off >>= 1) {
        a  += __shfl_down(a,  off, 64);
        b2 += __shfl_down(b2, off, 64);
    }
    if ((tid & 63) == 0) { red[tid >> 6] = a; red[16 + (tid >> 6)] = b2; }
    __syncthreads();
    if (tid == 0) {
        float x = 0.f, y = 0.f;
#pragma unroll
        for (int i = 0; i < 16; ++i) { x += red[i]; y += red[16 + i]; }
        bc[0] = x; bc[1] = y;
    }
    __syncthreads();
    a = bc[0]; b2 = bc[1];
}

// normalize y (scale r, bias c = -m*r), pointwise wp -> gelu -> g[4];
// accumulate concat-LN stats (cs1,cs2) and the 16 t16a accumulators from the
// LDS-staged c2w transpose slice for this d (16 x f4, wave-uniform broadcast).
__device__ __forceinline__ void pw_accum(const float y[4], float r, float c,
    const float* __restrict__ wp, const float* __restrict__ cw, int cwo,
    const f4* c2wTd, float& cs1, float& cs2, float* t16a, float g[4]) {
    float yn[4];
#pragma unroll
    for (int o = 0; o < 4; ++o) yn[o] = fmaf(y[o], r, c);
#pragma unroll
    for (int o = 0; o < 4; ++o) {
        float zz = fmaf(yn[0], wp[o*4+0], fmaf(yn[1], wp[o*4+1],
                   fmaf(yn[2], wp[o*4+2], yn[3] * wp[o*4+3])));
        g[o] = gelu_f(zz);
    }
#pragma unroll
    for (int o = 0; o < 4; ++o) { cs1 += g[o]; cs2 = fmaf(g[o], g[o], cs2); }
    float u[4];
#pragma unroll
    for (int co = 0; co < 4; ++co)
        u[co] = fmaf(g[0], cw[co*12+cwo+0], fmaf(g[1], cw[co*12+cwo+1],
                fmaf(g[2], cw[co*12+cwo+2], g[3] * cw[co*12+cwo+3])));
#pragma unroll
    for (int o = 0; o < 16; ++o) {
        f4 p = c2wTd[o];
        t16a[o] = fmaf(u[0], p.x, fmaf(u[1], p.y,
                  fmaf(u[2], p.z, fmaf(u[3], p.w, t16a[o]))));
    }
}

__global__ __launch_bounds__(1024)
void tcn_fused(const float* __restrict__ sIn, const float* __restrict__ wIn,
               const float* __restrict__ w1d, const float* __restrict__ w1p,
               const float* __restrict__ w2d, const float* __restrict__ w2p,
               const float* __restrict__ w3d, const float* __restrict__ w3p,
               const float* __restrict__ cw,  const float* __restrict__ c2w,
               const float* __restrict__ c3w, float* __restrict__ out,
               f4* __restrict__ baseT) {
    const int b   = blockIdx.x;
    const int tid = threadIdx.x;
    const int a   = tid & 511;              // row
    const int h   = tid >> 9;               // d-half: 0 -> [0,32), 1 -> [32,64)
    const int Dlo = h << 5;

    __shared__ float red[32];
    __shared__ float bc[2];
    __shared__ float Klds[16];
    // halo slot [a][0] = base[30],[31] (from h=0); [a][1] = base[32],[33] (from h=1)
    __shared__ f4 haloA[512][2][2];          // base2 seam values
    __shared__ f4 haloB[512][2][2];          // base3 seam values
    __shared__ float t16p[512][17];          // h=1 partial t16a (stride 17)
    __shared__ __align__(16) float c2wT[64 * 64];   // [d][o*4+co]

    // stage c2w transposed: c2wT[d*64 + o*4 + co] = c2w[o*256 + co*64 + d]
    for (int idx = tid; idx < 4096; idx += 1024) {
        int d = idx >> 6, rem = idx & 63, o = rem >> 2, co = rem & 3;
        c2wT[idx] = c2w[o * 256 + co * 64 + d];
    }

    // K[o] = sum_{co,d} c2w[o,co,d] * (sum_{j<12} cw[co*12+j])
    if (tid < 16) {
        float k = 0.f;
        for (int co = 0; co < 4; ++co) {
            float csum = 0.f;
            for (int j = 0; j < 12; ++j) csum += cw[co * 12 + j];
            const float* p = c2w + tid * 256 + co * 64;
            float t = 0.f;
            for (int d = 0; d < 64; ++d) t += p[d];
            k = fmaf(csum, t, k);
        }
        Klds[tid] = k;
    }

    const f4* srow = (const f4*)sIn + ((size_t)b * 512 + a) * 64;  // s: [b][a][d] f4
    f4* brow = baseT + (size_t)b * (64 * 512) + a;                 // base: [b][d][a] f4
    const f4 z4 = make_float4(0.f, 0.f, 0.f, 0.f);
    const float NY = 4.f * 512.f * 64.f;                           // 131072

    auto ldS = [&](int d) -> f4 { return ((unsigned)d < 64u) ? srow[d] : z4; };

    // ---------- Phase A: stats of y1 = conv(s) ----------
    float s1 = 0.f, s2 = 0.f;
    {
        f4 wA = ldS(Dlo - 2), wB = ldS(Dlo - 1), wC = ldS(Dlo), wD = ldS(Dlo + 1), wE;
        for (int i = 0; i < 32; ++i) {
            wE = ldS(Dlo + i + 2);
            float y[4]; conv4(wA, wC, wE, w1d, y);
            acc_stats(y, s1, s2);
            wA = wB; wB = wC; wC = wD; wD = wE;
        }
    }
    block_red2(s1, s2, red, bc, tid);
    float m1 = s1 / NY;
    float r1 = rsqrtf(s2 / NY - m1 * m1 + EPS_LN);
    float c1n = -m1 * r1;

    float t16a[16];
#pragma unroll
    for (int o = 0; o < 16; ++o) t16a[o] = 0.f;
    float cs1 = 0.f, cs2 = 0.f;

    // ---------- Phase B: x1, store base2 = s+x1, FUSED y2-stats, seam deferred ----------
    float q1 = 0.f, q2 = 0.f;
    f4 b0, b1, b2, b3, pm1, pm2, pm3, pm4;
    {
        f4 wA = ldS(Dlo - 2), wB = ldS(Dlo - 1), wC = ldS(Dlo), wD = ldS(Dlo + 1), wE;
        pm1 = pm2 = pm3 = pm4 = z4;
        b0 = b1 = b2 = b3 = z4;
        for (int i = 0; i < 32; ++i) {
            const int d = Dlo + i;
            wE = ldS(d + 2);
            float y[4]; conv4(wA, wC, wE, w1d, y);
            float g[4];
            pw_accum(y, r1, c1n, w1p, cw, 0, (const f4*)c2wT + d * 16, cs1, cs2, t16a, g);
            f4 nb;
            nb.x = wC.x + g[0]; nb.y = wC.y + g[1];
            nb.z = wC.z + g[2]; nb.w = wC.w + g[3];
            brow[(size_t)d * 512] = nb;
            if (i == 0) b0 = nb; else if (i == 1) b1 = nb;
            else if (i == 2) b2 = nb; else if (i == 3) b3 = nb;
            if (i >= 4) {            // y2 at e=d-2: taps base2[d-4], base2[d-2], base2[d]
                float y2[4]; conv4(pm4, pm2, nb, w2d, y2);
                acc_stats(y2, q1, q2);
            }
            pm4 = pm3; pm3 = pm2; pm2 = pm1; pm1 = nb;
            wA = wB; wB = wC; wC = wD; wD = wE;
        }
        // h=0 exports base2[30],[31] (pm2,pm1); h=1 exports base2[32],[33] (b0,b1)
        haloA[a][h][0] = h ? b0 : pm2;
        haloA[a][h][1] = h ? b1 : pm1;
    }
    __syncthreads();
    {   // deferred seam rows of y2: e = Dlo, Dlo+1, Dlo+30, Dlo+31
        f4 hlo0 = h ? haloA[a][0][0] : z4;   // base2[Dlo-2]
        f4 hlo1 = h ? haloA[a][0][1] : z4;   // base2[Dlo-1]
        f4 hhi0 = h ? z4 : haloA[a][1][0];   // base2[Dlo+32]
        f4 hhi1 = h ? z4 : haloA[a][1][1];   // base2[Dlo+33]
        float y2[4];
        conv4(hlo0, b0, b2, w2d, y2);  acc_stats(y2, q1, q2);   // e=Dlo
        conv4(hlo1, b1, b3, w2d, y2);  acc_stats(y2, q1, q2);   // e=Dlo+1
        conv4(pm4, pm2, hhi0, w2d, y2); acc_stats(y2, q1, q2);  // e=Dlo+30
        conv4(pm3, pm1, hhi1, w2d, y2); acc_stats(y2, q1, q2);  // e=Dlo+31
    }
    block_red2(q1, q2, red, bc, tid);
    float m2s = q1 / NY;
    float r2s = rsqrtf(q2 / NY - m2s * m2s + EPS_LN);
    float c2n = -m2s * r2s;

    // ---------- Phase C: x2, base3 = base2+x2 in place, FUSED y3-stats ----------
    // Own-range base2[d+2] is read at iter i, overwritten (as base3) at iter i+2;
    // partner-range values only via haloA. Race-free.
    float q31 = 0.f, q32 = 0.f;
    f4 cc0, cc1, cc2, cc3;
    {
        f4 vA = h ? haloA[a][0][0] : z4;
        f4 vB = h ? haloA[a][0][1] : z4;
        f4 vC = brow[(size_t)Dlo * 512];
        f4 vD = brow[(size_t)(Dlo + 1) * 512];
        f4 vE;
        pm1 = pm2 = pm3 = pm4 = z4;
        cc0 = cc1 = cc2 = cc3 = z4;
        for (int i = 0; i < 32; ++i) {
            const int d = Dlo + i;
            if (i < 30) vE = brow[(size_t)(d + 2) * 512];
            else        vE = h ? z4 : haloA[a][1][i - 30];
            float y[4]; conv4(vA, vC, vE, w2d, y);
            float g[4];
            pw_accum(y, r2s, c2n, w2p, cw, 4, (const f4*)c2wT + d * 16, cs1, cs2, t16a, g);
            f4 nb;
            nb.x = vC.x + g[0]; nb.y = vC.y + g[1];
            nb.z = vC.z + g[2]; nb.w = vC.w + g[3];
            brow[(size_t)d * 512] = nb;
            if (i == 0) cc0 = nb; else if (i == 1) cc1 = nb;
            else if (i == 2) cc2 = nb; else if (i == 3) cc3 = nb;
            if (i >= 4) {            // y3 at e=d-2
                float y3[4]; conv4(pm4, pm2, nb, w3d, y3);
                acc_stats(y3, q31, q32);
            }
            pm4 = pm3; pm3 = pm2; pm2 = pm1; pm1 = nb;
            vA = vB; vB = vC; vC = vD; vD = vE;
        }
        haloB[a][h][0] = h ? cc0 : pm2;
        haloB[a][h][1] = h ? cc1 : pm1;
    }
    __syncthreads();
    {   // deferred seam rows of y3
        f4 hlo0 = h ? haloB[a][0][0] : z4;
        f4 hlo1 = h ? haloB[a][0][1] : z4;
        f4 hhi0 = h ? z4 : haloB[a][1][0];
        f4 hhi1 = h ? z4 : haloB[a][1][1];
        float y3[4];
        conv4(hlo0, cc0, cc2, w3d, y3);  acc_stats(y3, q31, q32);
        conv4(hlo1, cc1, cc3, w3d, y3);  acc_stats(y3, q31, q32);
        conv4(pm4, pm2, hhi0, w3d, y3);  acc_stats(y3, q31, q32);
        conv4(pm3, pm1, hhi1, w3d, y3);  acc_stats(y3, q31, q32);
    }
    block_red2(q31, q32, red, bc, tid);
    float m3s = q31 / NY;
    float r3s = rsqrtf(q32 / NY - m3s * m3s + EPS_LN);
    float c3n = -m3s * r3s;

    // ---------- Phase D: x3 (read base3, seam via haloB) ----------
    {
        f4 wA = h ? haloB[a][0][0] : z4;
        f4 wB = h ? haloB[a][0][1] : z4;
        f4 wC = brow[(size_t)Dlo * 512];
        f4 wD = brow[(size_t)(Dlo + 1) * 512];
        f4 wE;
        for (int i = 0; i < 32; ++i) {
            const int d = Dlo + i;
            if (i < 30) wE = brow[(size_t)(d + 2) * 512];
            else        wE = h ? z4 : haloB[a][1][i - 30];
            float y[4]; conv4(wA, wC, wE, w3d, y);
            float g[4];
            pw_accum(y, r3s, c3n, w3p, cw, 8, (const f4*)c2wT + d * 16, cs1, cs2, t16a, g);
            wA = wB; wB = wC; wC = wD; wD = wE;
        }
    }

    // ---------- combine t16a partials + concat LN stats over [12,A,D] ----------
    if (h == 1) {
#pragma unroll
        for (int o = 0; o < 16; ++o) t16p[a][o] = t16a[o];
    }
    block_red2(cs1, cs2, red, bc, tid);        // syncs also publish t16p
    const float NC = 12.f * 512.f * 64.f;      // 393216
    float mcat = cs1 / NC;
    float rcat = rsqrtf(cs2 / NC - mcat * mcat + EPS_LN);

    // t16 values for this row (h=0 threads own the tail); LN over [16, A]
    float tv[16];
    float p1 = 0.f, p2 = 0.f;
    if (h == 0) {
#pragma unroll
        for (int o = 0; o < 16; ++o) {
            float tot = t16a[o] + t16p[a][o];
            float v = rcat * (tot - mcat * Klds[o]);
            tv[o] = v; p1 += v; p2 = fmaf(v, v, p2);
        }
    }
    block_red2(p1, p2, red, bc, tid);
    const float N16 = 16.f * 512.f;            // 8192
    float m16 = p1 / N16;
    float r16 = rsqrtf(p2 / N16 - m16 * m16 + EPS_LN);

    // c3w over 17 channels (16 normalized + raw w), then LN over A
    float v = 0.f, f1 = 0.f, f2 = 0.f;
    if (h == 0) {
        v = wIn[(size_t)b * 512 + a] * c3w[16];
#pragma unroll
        for (int o = 0; o < 16; ++o) v = fmaf((tv[o] - m16) * r16, c3w[o], v);
        f1 = v; f2 = v * v;
    }
    block_red2(f1, f2, red, bc, tid);
    float mA = f1 / 512.f;
    float rA = rsqrtf(f2 / 512.f - mA * mA + EPS_LN);
    if (h == 0) out[(size_t)b * 512 + a] = (v - mA) * rA;
}

extern "C" void kernel_launch(void* const* d_in, const int* in_sizes, int n_in,
                              void* d_out, int out_size, void* d_ws, size_t ws_size,
                              hipStream_t stream) {
    const float* s   = (const float*)d_in[0];
    const float* w   = (const float*)d_in[1];
    const float* w1d = (const float*)d_in[2];
    const float* w1p = (const float*)d_in[3];
    const float* w2d = (const float*)d_in[4];
    const float* w2p = (const float*)d_in[5];
    const float* w3d = (const float*)d_in[6];
    const float* w3p = (const float*)d_in[7];
    const float* cw  = (const float*)d_in[8];
    const float* c2w = (const float*)d_in[9];
    const float* c3w = (const float*)d_in[10];
    tcn_fused<<<dim3(256), dim3(1024), 0, stream>>>(
        s, w, w1d, w1p, w2d, w2p, w3d, w3p, cw, c2w, c3w,
        (float*)d_out, (f4*)d_ws);
}

// Round 3
// 1127.612 us; speedup vs baseline: 1.0025x; 1.0025x over previous
//
#include <hip/hip_runtime.h>
#include <math.h>

// CNN_tcn, fused d-split: one block per sample (grid 256), 1024 threads =
// 2 threads per row a; thread (a,h) owns d in [32h, 32h+32).
// y2/y3 stats are FUSED into the production passes (rolling window of
// just-produced values); the 4 seam rows per thread are deferred and fixed
// up from LDS halos after a sync. c2w staged in LDS transposed [d][o][co].
// __launch_bounds__(1024, 4): 4 waves/EU -> 128-VGPR cap. Without the second
// arg the allocator targeted 8 waves/EU (64 VGPRs) and spilled ~35 regs of
// the ~100-reg live set to scratch -> 2.7 GB of phantom HBM traffic (round 2:
// FETCH 1.5 GB / WRITE 2.0 GB vs ideal 0.54/0.27 GB). LDS (117 KB) limits us
// to 1 block/CU = 4 waves/EU regardless, so the extra registers are free.
// Workspace: ONE [B][D][A] float4 buffer (128 MiB), base2 -> base3 in place;
// all global RAW is same-thread, partner data only via LDS halos.

#define EPS_LN 1e-5f
typedef float4 f4;

__device__ __forceinline__ float gelu_f(float v) {
    return 0.5f * v * (1.0f + erff(v * 0.70710678118654752440f));
}

// y[o] = dilated conv taps: a = base[d-2], c = base[d], e = base[d+2]
// wd layout (4,4,1,3): [o][cin][k] flat o*12 + cin*3 + k
__device__ __forceinline__ void conv4(const f4 a, const f4 c, const f4 e,
                                      const float* __restrict__ wd, float y[4]) {
#pragma unroll
    for (int o = 0; o < 4; ++o) {
        const float* wv = wd + o * 12;
        y[o] = fmaf(a.x, wv[0], fmaf(c.x, wv[1], fmaf(e.x, wv[2],
               fmaf(a.y, wv[3], fmaf(c.y, wv[4], fmaf(e.y, wv[5],
               fmaf(a.z, wv[6], fmaf(c.z, wv[7], fmaf(e.z, wv[8],
               fmaf(a.w, wv[9], fmaf(c.w, wv[10], e.w * wv[11])))))))))));
    }
}

__device__ __forceinline__ void acc_stats(const float y[4], float& s1, float& s2) {
#pragma unroll
    for (int o = 0; o < 4; ++o) { s1 += y[o]; s2 = fmaf(y[o], y[o], s2); }
}

// block-wide reduce of (a,b2) over 1024 threads (16 waves)
__device__ __forceinline__ void block_red2(float& a, float& b2, float* red,
                                           float* bc, int tid) {
#pragma unroll
    for (int off = 32; off > 0; off >>= 1) {
        a  += __shfl_down(a,  off, 64);
        b2 += __shfl_down(b2, off, 64);
    }
    if ((tid & 63) == 0) { red[tid >> 6] = a; red[16 + (tid >> 6)] = b2; }
    __syncthreads();
    if (tid == 0) {
        float x = 0.f, y = 0.f;
#pragma unroll
        for (int i = 0; i < 16; ++i) { x += red[i]; y += red[16 + i]; }
        bc[0] = x; bc[1] = y;
    }
    __syncthreads();
    a = bc[0]; b2 = bc[1];
}

// normalize y (scale r, bias c = -m*r), pointwise wp -> gelu -> g[4];
// accumulate concat-LN stats (cs1,cs2) and the 16 t16a accumulators from the
// LDS-staged c2w transpose slice for this d (16 x f4, wave-uniform broadcast).
__device__ __forceinline__ void pw_accum(const float y[4], float r, float c,
    const float* __restrict__ wp, const float* __restrict__ cw, int cwo,
    const f4* c2wTd, float& cs1, float& cs2, float* t16a, float g[4]) {
    float yn[4];
#pragma unroll
    for (int o = 0; o < 4; ++o) yn[o] = fmaf(y[o], r, c);
#pragma unroll
    for (int o = 0; o < 4; ++o) {
        float zz = fmaf(yn[0], wp[o*4+0], fmaf(yn[1], wp[o*4+1],
                   fmaf(yn[2], wp[o*4+2], yn[3] * wp[o*4+3])));
        g[o] = gelu_f(zz);
    }
#pragma unroll
    for (int o = 0; o < 4; ++o) { cs1 += g[o]; cs2 = fmaf(g[o], g[o], cs2); }
    float u[4];
#pragma unroll
    for (int co = 0; co < 4; ++co)
        u[co] = fmaf(g[0], cw[co*12+cwo+0], fmaf(g[1], cw[co*12+cwo+1],
                fmaf(g[2], cw[co*12+cwo+2], g[3] * cw[co*12+cwo+3])));
#pragma unroll
    for (int o = 0; o < 16; ++o) {
        f4 p = c2wTd[o];
        t16a[o] = fmaf(u[0], p.x, fmaf(u[1], p.y,
                  fmaf(u[2], p.z, fmaf(u[3], p.w, t16a[o]))));
    }
}

__global__ __launch_bounds__(1024, 4)
void tcn_fused(const float* __restrict__ sIn, const float* __restrict__ wIn,
               const float* __restrict__ w1d, const float* __restrict__ w1p,
               const float* __restrict__ w2d, const float* __restrict__ w2p,
               const float* __restrict__ w3d, const float* __restrict__ w3p,
               const float* __restrict__ cw,  const float* __restrict__ c2w,
               const float* __restrict__ c3w, float* __restrict__ out,
               f4* __restrict__ baseT) {
    const int b   = blockIdx.x;
    const int tid = threadIdx.x;
    const int a   = tid & 511;              // row
    const int h   = tid >> 9;               // d-half: 0 -> [0,32), 1 -> [32,64)
    const int Dlo = h << 5;

    __shared__ float red[32];
    __shared__ float bc[2];
    __shared__ float Klds[16];
    // halo slot [a][0] = base[30],[31] (from h=0); [a][1] = base[32],[33] (from h=1)
    __shared__ f4 haloA[512][2][2];          // base2 seam values
    __shared__ f4 haloB[512][2][2];          // base3 seam values
    __shared__ float t16p[512][17];          // h=1 partial t16a (stride 17)
    __shared__ __align__(16) float c2wT[64 * 64];   // [d][o*4+co]

    // stage c2w transposed: c2wT[d*64 + o*4 + co] = c2w[o*256 + co*64 + d]
    for (int idx = tid; idx < 4096; idx += 1024) {
        int d = idx >> 6, rem = idx & 63, o = rem >> 2, co = rem & 3;
        c2wT[idx] = c2w[o * 256 + co * 64 + d];
    }

    // K[o] = sum_{co,d} c2w[o,co,d] * (sum_{j<12} cw[co*12+j])
    if (tid < 16) {
        float k = 0.f;
        for (int co = 0; co < 4; ++co) {
            float csum = 0.f;
            for (int j = 0; j < 12; ++j) csum += cw[co * 12 + j];
            const float* p = c2w + tid * 256 + co * 64;
            float t = 0.f;
            for (int d = 0; d < 64; ++d) t += p[d];
            k = fmaf(csum, t, k);
        }
        Klds[tid] = k;
    }

    const f4* srow = (const f4*)sIn + ((size_t)b * 512 + a) * 64;  // s: [b][a][d] f4
    f4* brow = baseT + (size_t)b * (64 * 512) + a;                 // base: [b][d][a] f4
    const f4 z4 = make_float4(0.f, 0.f, 0.f, 0.f);
    const float NY = 4.f * 512.f * 64.f;                           // 131072

    auto ldS = [&](int d) -> f4 { return ((unsigned)d < 64u) ? srow[d] : z4; };

    // ---------- Phase A: stats of y1 = conv(s) ----------
    float s1 = 0.f, s2 = 0.f;
    {
        f4 wA = ldS(Dlo - 2), wB = ldS(Dlo - 1), wC = ldS(Dlo), wD = ldS(Dlo + 1), wE;
        for (int i = 0; i < 32; ++i) {
            wE = ldS(Dlo + i + 2);
            float y[4]; conv4(wA, wC, wE, w1d, y);
            acc_stats(y, s1, s2);
            wA = wB; wB = wC; wC = wD; wD = wE;
        }
    }
    block_red2(s1, s2, red, bc, tid);
    float m1 = s1 / NY;
    float r1 = rsqrtf(s2 / NY - m1 * m1 + EPS_LN);
    float c1n = -m1 * r1;

    float t16a[16];
#pragma unroll
    for (int o = 0; o < 16; ++o) t16a[o] = 0.f;
    float cs1 = 0.f, cs2 = 0.f;

    // ---------- Phase B: x1, store base2 = s+x1, FUSED y2-stats, seam deferred ----------
    float q1 = 0.f, q2 = 0.f;
    f4 b0, b1, b2, b3, pm1, pm2, pm3, pm4;
    {
        f4 wA = ldS(Dlo - 2), wB = ldS(Dlo - 1), wC = ldS(Dlo), wD = ldS(Dlo + 1), wE;
        pm1 = pm2 = pm3 = pm4 = z4;
        b0 = b1 = b2 = b3 = z4;
        for (int i = 0; i < 32; ++i) {
            const int d = Dlo + i;
            wE = ldS(d + 2);
            float y[4]; conv4(wA, wC, wE, w1d, y);
            float g[4];
            pw_accum(y, r1, c1n, w1p, cw, 0, (const f4*)c2wT + d * 16, cs1, cs2, t16a, g);
            f4 nb;
            nb.x = wC.x + g[0]; nb.y = wC.y + g[1];
            nb.z = wC.z + g[2]; nb.w = wC.w + g[3];
            brow[(size_t)d * 512] = nb;
            if (i == 0) b0 = nb; else if (i == 1) b1 = nb;
            else if (i == 2) b2 = nb; else if (i == 3) b3 = nb;
            if (i >= 4) {            // y2 at e=d-2: taps base2[d-4], base2[d-2], base2[d]
                float y2[4]; conv4(pm4, pm2, nb, w2d, y2);
                acc_stats(y2, q1, q2);
            }
            pm4 = pm3; pm3 = pm2; pm2 = pm1; pm1 = nb;
            wA = wB; wB = wC; wC = wD; wD = wE;
        }
        // h=0 exports base2[30],[31] (pm2,pm1); h=1 exports base2[32],[33] (b0,b1)
        haloA[a][h][0] = h ? b0 : pm2;
        haloA[a][h][1] = h ? b1 : pm1;
    }
    __syncthreads();
    {   // deferred seam rows of y2: e = Dlo, Dlo+1, Dlo+30, Dlo+31
        f4 hlo0 = h ? haloA[a][0][0] : z4;   // base2[Dlo-2]
        f4 hlo1 = h ? haloA[a][0][1] : z4;   // base2[Dlo-1]
        f4 hhi0 = h ? z4 : haloA[a][1][0];   // base2[Dlo+32]
        f4 hhi1 = h ? z4 : haloA[a][1][1];   // base2[Dlo+33]
        float y2[4];
        conv4(hlo0, b0, b2, w2d, y2);  acc_stats(y2, q1, q2);   // e=Dlo
        conv4(hlo1, b1, b3, w2d, y2);  acc_stats(y2, q1, q2);   // e=Dlo+1
        conv4(pm4, pm2, hhi0, w2d, y2); acc_stats(y2, q1, q2);  // e=Dlo+30
        conv4(pm3, pm1, hhi1, w2d, y2); acc_stats(y2, q1, q2);  // e=Dlo+31
    }
    block_red2(q1, q2, red, bc, tid);
    float m2s = q1 / NY;
    float r2s = rsqrtf(q2 / NY - m2s * m2s + EPS_LN);
    float c2n = -m2s * r2s;

    // ---------- Phase C: x2, base3 = base2+x2 in place, FUSED y3-stats ----------
    // Own-range base2[d+2] is read at iter i, overwritten (as base3) at iter i+2;
    // partner-range values only via haloA. Race-free.
    float q31 = 0.f, q32 = 0.f;
    f4 cc0, cc1, cc2, cc3;
    {
        f4 vA = h ? haloA[a][0][0] : z4;
        f4 vB = h ? haloA[a][0][1] : z4;
        f4 vC = brow[(size_t)Dlo * 512];
        f4 vD = brow[(size_t)(Dlo + 1) * 512];
        f4 vE;
        pm1 = pm2 = pm3 = pm4 = z4;
        cc0 = cc1 = cc2 = cc3 = z4;
        for (int i = 0; i < 32; ++i) {
            const int d = Dlo + i;
            if (i < 30) vE = brow[(size_t)(d + 2) * 512];
            else        vE = h ? z4 : haloA[a][1][i - 30];
            float y[4]; conv4(vA, vC, vE, w2d, y);
            float g[4];
            pw_accum(y, r2s, c2n, w2p, cw, 4, (const f4*)c2wT + d * 16, cs1, cs2, t16a, g);
            f4 nb;
            nb.x = vC.x + g[0]; nb.y = vC.y + g[1];
            nb.z = vC.z + g[2]; nb.w = vC.w + g[3];
            brow[(size_t)d * 512] = nb;
            if (i == 0) cc0 = nb; else if (i == 1) cc1 = nb;
            else if (i == 2) cc2 = nb; else if (i == 3) cc3 = nb;
            if (i >= 4) {            // y3 at e=d-2
                float y3[4]; conv4(pm4, pm2, nb, w3d, y3);
                acc_stats(y3, q31, q32);
            }
            pm4 = pm3; pm3 = pm2; pm2 = pm1; pm1 = nb;
            vA = vB; vB = vC; vC = vD; vD = vE;
        }
        haloB[a][h][0] = h ? cc0 : pm2;
        haloB[a][h][1] = h ? cc1 : pm1;
    }
    __syncthreads();
    {   // deferred seam rows of y3
        f4 hlo0 = h ? haloB[a][0][0] : z4;
        f4 hlo1 = h ? haloB[a][0][1] : z4;
        f4 hhi0 = h ? z4 : haloB[a][1][0];
        f4 hhi1 = h ? z4 : haloB[a][1][1];
        float y3[4];
        conv4(hlo0, cc0, cc2, w3d, y3);  acc_stats(y3, q31, q32);
        conv4(hlo1, cc1, cc3, w3d, y3);  acc_stats(y3, q31, q32);
        conv4(pm4, pm2, hhi0, w3d, y3);  acc_stats(y3, q31, q32);
        conv4(pm3, pm1, hhi1, w3d, y3);  acc_stats(y3, q31, q32);
    }
    block_red2(q31, q32, red, bc, tid);
    float m3s = q31 / NY;
    float r3s = rsqrtf(q32 / NY - m3s * m3s + EPS_LN);
    float c3n = -m3s * r3s;

    // ---------- Phase D: x3 (read base3, seam via haloB) ----------
    {
        f4 wA = h ? haloB[a][0][0] : z4;
        f4 wB = h ? haloB[a][0][1] : z4;
        f4 wC = brow[(size_t)Dlo * 512];
        f4 wD = brow[(size_t)(Dlo + 1) * 512];
        f4 wE;
        for (int i = 0; i < 32; ++i) {
            const int d = Dlo + i;
            if (i < 30) wE = brow[(size_t)(d + 2) * 512];
            else        wE = h ? z4 : haloB[a][1][i - 30];
            float y[4]; conv4(wA, wC, wE, w3d, y);
            float g[4];
            pw_accum(y, r3s, c3n, w3p, cw, 8, (const f4*)c2wT + d * 16, cs1, cs2, t16a, g);
            wA = wB; wB = wC; wC = wD; wD = wE;
        }
    }

    // ---------- combine t16a partials + concat LN stats over [12,A,D] ----------
    if (h == 1) {
#pragma unroll
        for (int o = 0; o < 16; ++o) t16p[a][o] = t16a[o];
    }
    block_red2(cs1, cs2, red, bc, tid);        // syncs also publish t16p
    const float NC = 12.f * 512.f * 64.f;      // 393216
    float mcat = cs1 / NC;
    float rcat = rsqrtf(cs2 / NC - mcat * mcat + EPS_LN);

    // t16 values for this row (h=0 threads own the tail); LN over [16, A]
    float tv[16];
    float p1 = 0.f, p2 = 0.f;
    if (h == 0) {
#pragma unroll
        for (int o = 0; o < 16; ++o) {
            float tot = t16a[o] + t16p[a][o];
            float v = rcat * (tot - mcat * Klds[o]);
            tv[o] = v; p1 += v; p2 = fmaf(v, v, p2);
        }
    }
    block_red2(p1, p2, red, bc, tid);
    const float N16 = 16.f * 512.f;            // 8192
    float m16 = p1 / N16;
    float r16 = rsqrtf(p2 / N16 - m16 * m16 + EPS_LN);

    // c3w over 17 channels (16 normalized + raw w), then LN over A
    float v = 0.f, f1 = 0.f, f2 = 0.f;
    if (h == 0) {
        v = wIn[(size_t)b * 512 + a] * c3w[16];
#pragma unroll
        for (int o = 0; o < 16; ++o) v = fmaf((tv[o] - m16) * r16, c3w[o], v);
        f1 = v; f2 = v * v;
    }
    block_red2(f1, f2, red, bc, tid);
    float mA = f1 / 512.f;
    float rA = rsqrtf(f2 / 512.f - mA * mA + EPS_LN);
    if (h == 0) out[(size_t)b * 512 + a] = (v - mA) * rA;
}

extern "C" void kernel_launch(void* const* d_in, const int* in_sizes, int n_in,
                              void* d_out, int out_size, void* d_ws, size_t ws_size,
                              hipStream_t stream) {
    const float* s   = (const float*)d_in[0];
    const float* w   = (const float*)d_in[1];
    const float* w1d = (const float*)d_in[2];
    const float* w1p = (const float*)d_in[3];
    const float* w2d = (const float*)d_in[4];
    const float* w2p = (const float*)d_in[5];
    const float* w3d = (const float*)d_in[6];
    const float* w3p = (const float*)d_in[7];
    const float* cw  = (const float*)d_in[8];
    const float* c2w = (const float*)d_in[9];
    const float* c3w = (const float*)d_in[10];
    tcn_fused<<<dim3(256), dim3(1024), 0, stream>>>(
        s, w, w1d, w1p, w2d, w2p, w3d, w3p, cw, c2w, c3w,
        (float*)d_out, (f4*)d_ws);
}

// Round 4
// 784.374 us; speedup vs baseline: 1.4412x; 1.4376x over previous
//
#include <hip/hip_runtime.h>
#include <math.h>

// CNN_tcn, fused d-split v2: one block per sample (grid 256), 1024 threads =
// 2 threads per row a; thread (a,h) owns d in [32h, 32h+32).
// y2/y3 stats FUSED into the production passes (rolling pm window). Seam
// handling redesigned to eliminate the b0..b3/cc0..cc3 capture registers
// (rounds 2/3 spilled ~30 regs -> 2.6 GB phantom scratch traffic at the
// 64-VGPR budget):
//   - h=0 head rows (e=Dlo,Dlo+1): a-tap is zero -> computed IN-loop at i=2,3.
//   - h=1 head captures (base[32..35]) written to LDS seamH at production.
//   - h=1 tail rows (e=62,63): e-tap is zero -> computed at loop end from pms.
//   - only 2 rows/thread deferred past the barrier (use pm regs + LDS).
// Occupancy pinned with amdgpu_waves_per_eu(4,4): LDS (146 KB) allows exactly
// 1 block/CU = 16 waves = 4 waves/EU, so the register budget is 512/4 = 128.
// (__launch_bounds__(1024,4) was ignored: VGPR stayed 64 and spilled.)
// Workspace: ONE [B][D][A] float4 buffer, base2 -> base3 in place; all global
// RAW is same-thread, partner data only via LDS.

#define EPS_LN 1e-5f
typedef float4 f4;

__device__ __forceinline__ float gelu_f(float v) {
    return 0.5f * v * (1.0f + erff(v * 0.70710678118654752440f));
}

// y[o] = dilated conv taps: a = base[d-2], c = base[d], e = base[d+2]
// wd layout (4,4,1,3): [o][cin][k] flat o*12 + cin*3 + k
__device__ __forceinline__ void conv4(const f4 a, const f4 c, const f4 e,
                                      const float* __restrict__ wd, float y[4]) {
#pragma unroll
    for (int o = 0; o < 4; ++o) {
        const float* wv = wd + o * 12;
        y[o] = fmaf(a.x, wv[0], fmaf(c.x, wv[1], fmaf(e.x, wv[2],
               fmaf(a.y, wv[3], fmaf(c.y, wv[4], fmaf(e.y, wv[5],
               fmaf(a.z, wv[6], fmaf(c.z, wv[7], fmaf(e.z, wv[8],
               fmaf(a.w, wv[9], fmaf(c.w, wv[10], e.w * wv[11])))))))))));
    }
}

__device__ __forceinline__ void acc_stats(const float y[4], float& s1, float& s2) {
#pragma unroll
    for (int o = 0; o < 4; ++o) { s1 += y[o]; s2 = fmaf(y[o], y[o], s2); }
}

// block-wide reduce of (a,b2) over 1024 threads (16 waves)
__device__ __forceinline__ void block_red2(float& a, float& b2, float* red,
                                           float* bc, int tid) {
#pragma unroll
    for (int off = 32; off > 0; off >>= 1) {
        a  += __shfl_down(a,  off, 64);
        b2 += __shfl_down(b2, off, 64);
    }
    if ((tid & 63) == 0) { red[tid >> 6] = a; red[16 + (tid >> 6)] = b2; }
    __syncthreads();
    if (tid == 0) {
        float x = 0.f, y = 0.f;
#pragma unroll
        for (int i = 0; i < 16; ++i) { x += red[i]; y += red[16 + i]; }
        bc[0] = x; bc[1] = y;
    }
    __syncthreads();
    a = bc[0]; b2 = bc[1];
}

// normalize y (scale r, bias c = -m*r), pointwise wp -> gelu -> g[4];
// accumulate concat-LN stats (cs1,cs2) and the 16 t16a accumulators from the
// LDS-staged c2w transpose slice for this d (16 x f4, wave-uniform broadcast).
__device__ __forceinline__ void pw_accum(const float y[4], float r, float c,
    const float* __restrict__ wp, const float* __restrict__ cw, int cwo,
    const f4* c2wTd, float& cs1, float& cs2, float* t16a, float g[4]) {
    float yn[4];
#pragma unroll
    for (int o = 0; o < 4; ++o) yn[o] = fmaf(y[o], r, c);
#pragma unroll
    for (int o = 0; o < 4; ++o) {
        float zz = fmaf(yn[0], wp[o*4+0], fmaf(yn[1], wp[o*4+1],
                   fmaf(yn[2], wp[o*4+2], yn[3] * wp[o*4+3])));
        g[o] = gelu_f(zz);
    }
#pragma unroll
    for (int o = 0; o < 4; ++o) { cs1 += g[o]; cs2 = fmaf(g[o], g[o], cs2); }
    float u[4];
#pragma unroll
    for (int co = 0; co < 4; ++co)
        u[co] = fmaf(g[0], cw[co*12+cwo+0], fmaf(g[1], cw[co*12+cwo+1],
                fmaf(g[2], cw[co*12+cwo+2], g[3] * cw[co*12+cwo+3])));
#pragma unroll
    for (int o = 0; o < 16; ++o) {
        f4 p = c2wTd[o];
        t16a[o] = fmaf(u[0], p.x, fmaf(u[1], p.y,
                  fmaf(u[2], p.z, fmaf(u[3], p.w, t16a[o]))));
    }
}

__global__ __attribute__((amdgpu_flat_work_group_size(1024, 1024),
                          amdgpu_waves_per_eu(4, 4)))
void tcn_fused(const float* __restrict__ sIn, const float* __restrict__ wIn,
               const float* __restrict__ w1d, const float* __restrict__ w1p,
               const float* __restrict__ w2d, const float* __restrict__ w2p,
               const float* __restrict__ w3d, const float* __restrict__ w3p,
               const float* __restrict__ cw,  const float* __restrict__ c2w,
               const float* __restrict__ c3w, float* __restrict__ out,
               f4* __restrict__ baseT) {
    const int b   = blockIdx.x;
    const int tid = threadIdx.x;
    const int a   = tid & 511;              // row
    const int h   = tid >> 9;               // d-half: 0 -> [0,32), 1 -> [32,64)
    const int Dlo = h << 5;

    __shared__ float red[32];
    __shared__ float bc[2];
    __shared__ float Klds[16];
    __shared__ f4 seamHA[512][4];           // base2[32..35]  (written by h=1)
    __shared__ f4 seamHB[512][4];           // base3[32..35]  (written by h=1)
    __shared__ f4 tailA[512][2];            // base2[30..31]  (written by h=0)
    __shared__ f4 tailB[512][2];            // base3[30..31]  (written by h=0)
    __shared__ float t16p[512][17];         // h=1 partial t16a (stride 17)
    __shared__ __align__(16) float c2wT[64 * 64];   // [d][o*4+co]

    // stage c2w transposed: c2wT[d*64 + o*4 + co] = c2w[o*256 + co*64 + d]
    for (int idx = tid; idx < 4096; idx += 1024) {
        int d = idx >> 6, rem = idx & 63, o = rem >> 2, co = rem & 3;
        c2wT[idx] = c2w[o * 256 + co * 64 + d];
    }

    // K[o] = sum_{co,d} c2w[o,co,d] * (sum_{j<12} cw[co*12+j])
    if (tid < 16) {
        float k = 0.f;
        for (int co = 0; co < 4; ++co) {
            float csum = 0.f;
            for (int j = 0; j < 12; ++j) csum += cw[co * 12 + j];
            const float* p = c2w + tid * 256 + co * 64;
            float t = 0.f;
            for (int d = 0; d < 64; ++d) t += p[d];
            k = fmaf(csum, t, k);
        }
        Klds[tid] = k;
    }

    const f4* srow = (const f4*)sIn + ((size_t)b * 512 + a) * 64;  // s: [b][a][d] f4
    f4* brow = baseT + (size_t)b * (64 * 512) + a;                 // base: [b][d][a] f4
    const f4 z4 = make_float4(0.f, 0.f, 0.f, 0.f);
    const float NY = 4.f * 512.f * 64.f;                           // 131072

    auto ldS = [&](int d) -> f4 { return ((unsigned)d < 64u) ? srow[d] : z4; };

    // ---------- Phase A: stats of y1 = conv(s) ----------
    float s1 = 0.f, s2 = 0.f;
    {
        f4 wA = ldS(Dlo - 2), wB = ldS(Dlo - 1), wC = ldS(Dlo), wD = ldS(Dlo + 1), wE;
        for (int i = 0; i < 32; ++i) {
            wE = ldS(Dlo + i + 2);
            float y[4]; conv4(wA, wC, wE, w1d, y);
            acc_stats(y, s1, s2);
            wA = wB; wB = wC; wC = wD; wD = wE;
        }
    }
    block_red2(s1, s2, red, bc, tid);
    float m1 = s1 / NY;
    float r1 = rsqrtf(s2 / NY - m1 * m1 + EPS_LN);
    float c1n = -m1 * r1;

    float t16a[16];
#pragma unroll
    for (int o = 0; o < 16; ++o) t16a[o] = 0.f;
    float cs1 = 0.f, cs2 = 0.f;

    f4 pm1, pm2, pm3, pm4;    // rolling window of produced base values (nb(d-1..d-4))

    // ---------- Phase B: x1, store base2 = s+x1, FUSED y2-stats ----------
    float q1 = 0.f, q2 = 0.f;
    {
        f4 wA = ldS(Dlo - 2), wB = ldS(Dlo - 1), wC = ldS(Dlo), wD = ldS(Dlo + 1), wE;
        pm1 = pm2 = pm3 = pm4 = z4;
        for (int i = 0; i < 32; ++i) {
            const int d = Dlo + i;
            wE = ldS(d + 2);
            float y[4]; conv4(wA, wC, wE, w1d, y);
            float g[4];
            pw_accum(y, r1, c1n, w1p, cw, 0, (const f4*)c2wT + d * 16, cs1, cs2, t16a, g);
            f4 nb;
            nb.x = wC.x + g[0]; nb.y = wC.y + g[1];
            nb.z = wC.z + g[2]; nb.w = wC.w + g[3];
            brow[(size_t)d * 512] = nb;
            if (h && i < 4) seamHA[a][i] = nb;
            if (i >= 4) {                 // y2 row e=d-2: taps nb(d-4), nb(d-2), nb(d)
                float y2[4]; conv4(pm4, pm2, nb, w2d, y2);
                acc_stats(y2, q1, q2);
            } else if (i >= 2 && h == 0) { // e=0,1: a-tap out of range -> zero
                float y2[4]; conv4(z4, pm2, nb, w2d, y2);
                acc_stats(y2, q1, q2);
            }
            pm4 = pm3; pm3 = pm2; pm2 = pm1; pm1 = nb;
            wA = wB; wB = wC; wC = wD; wD = wE;
        }
        if (h) {   // tail rows e=62,63: e-tap out of range -> zero; immediate
            float y2[4];
            conv4(pm4, pm2, z4, w2d, y2); acc_stats(y2, q1, q2);
            conv4(pm3, pm1, z4, w2d, y2); acc_stats(y2, q1, q2);
        } else {   // export base2[30],[31] for partner
            tailA[a][0] = pm2; tailA[a][1] = pm1;
        }
    }
    __syncthreads();
    {   // deferred seam rows of y2 (2 per thread)
        float y2[4];
        if (h == 0) {   // e=30: taps nb(28),nb(30),base2[32]; e=31: nb(29),nb(31),base2[33]
            conv4(pm4, pm2, seamHA[a][0], w2d, y2); acc_stats(y2, q1, q2);
            conv4(pm3, pm1, seamHA[a][1], w2d, y2); acc_stats(y2, q1, q2);
        } else {        // e=32: base2[30],[32],[34]; e=33: base2[31],[33],[35]
            conv4(tailA[a][0], seamHA[a][0], seamHA[a][2], w2d, y2); acc_stats(y2, q1, q2);
            conv4(tailA[a][1], seamHA[a][1], seamHA[a][3], w2d, y2); acc_stats(y2, q1, q2);
        }
    }
    block_red2(q1, q2, red, bc, tid);
    float m2s = q1 / NY;
    float r2s = rsqrtf(q2 / NY - m2s * m2s + EPS_LN);
    float c2n = -m2s * r2s;

    // ---------- Phase C: x2, base3 = base2+x2 in place, FUSED y3-stats ----------
    // Own-range base2[d+2] is read at iter i, overwritten (as base3) at iter i+2;
    // partner-range base2 only via tailA/seamHA. Race-free.
    float q31 = 0.f, q32 = 0.f;
    {
        f4 vA = h ? tailA[a][0] : z4;
        f4 vB = h ? tailA[a][1] : z4;
        f4 vC = brow[(size_t)Dlo * 512];
        f4 vD = brow[(size_t)(Dlo + 1) * 512];
        f4 vE;
        pm1 = pm2 = pm3 = pm4 = z4;
        for (int i = 0; i < 32; ++i) {
            const int d = Dlo + i;
            if (i < 30) vE = brow[(size_t)(d + 2) * 512];
            else        vE = h ? z4 : seamHA[a][i - 30];   // base2[32],[33] (stage-A!)
            float y[4]; conv4(vA, vC, vE, w2d, y);
            float g[4];
            pw_accum(y, r2s, c2n, w2p, cw, 4, (const f4*)c2wT + d * 16, cs1, cs2, t16a, g);
            f4 nb;
            nb.x = vC.x + g[0]; nb.y = vC.y + g[1];
            nb.z = vC.z + g[2]; nb.w = vC.w + g[3];
            brow[(size_t)d * 512] = nb;
            if (h && i < 4) seamHB[a][i] = nb;
            if (i >= 4) {
                float y3[4]; conv4(pm4, pm2, nb, w3d, y3);
                acc_stats(y3, q31, q32);
            } else if (i >= 2 && h == 0) {
                float y3[4]; conv4(z4, pm2, nb, w3d, y3);
                acc_stats(y3, q31, q32);
            }
            pm4 = pm3; pm3 = pm2; pm2 = pm1; pm1 = nb;
            vA = vB; vB = vC; vC = vD; vD = vE;
        }
        if (h) {
            float y3[4];
            conv4(pm4, pm2, z4, w3d, y3); acc_stats(y3, q31, q32);
            conv4(pm3, pm1, z4, w3d, y3); acc_stats(y3, q31, q32);
        } else {
            tailB[a][0] = pm2; tailB[a][1] = pm1;
        }
    }
    __syncthreads();
    {   // deferred seam rows of y3
        float y3[4];
        if (h == 0) {
            conv4(pm4, pm2, seamHB[a][0], w3d, y3); acc_stats(y3, q31, q32);
            conv4(pm3, pm1, seamHB[a][1], w3d, y3); acc_stats(y3, q31, q32);
        } else {
            conv4(tailB[a][0], seamHB[a][0], seamHB[a][2], w3d, y3); acc_stats(y3, q31, q32);
            conv4(tailB[a][1], seamHB[a][1], seamHB[a][3], w3d, y3); acc_stats(y3, q31, q32);
        }
    }
    block_red2(q31, q32, red, bc, tid);
    float m3s = q31 / NY;
    float r3s = rsqrtf(q32 / NY - m3s * m3s + EPS_LN);
    float c3n = -m3s * r3s;

    // ---------- Phase D: x3 (read base3; partner seam via tailB/seamHB) ----------
    {
        f4 wA = h ? tailB[a][0] : z4;
        f4 wB = h ? tailB[a][1] : z4;
        f4 wC = brow[(size_t)Dlo * 512];
        f4 wD = brow[(size_t)(Dlo + 1) * 512];
        f4 wE;
        for (int i = 0; i < 32; ++i) {
            const int d = Dlo + i;
            if (i < 30) wE = brow[(size_t)(d + 2) * 512];
            else        wE = h ? z4 : seamHB[a][i - 30];
            float y[4]; conv4(wA, wC, wE, w3d, y);
            float g[4];
            pw_accum(y, r3s, c3n, w3p, cw, 8, (const f4*)c2wT + d * 16, cs1, cs2, t16a, g);
            wA = wB; wB = wC; wC = wD; wD = wE;
        }
    }

    // ---------- combine t16a partials + concat LN stats over [12,A,D] ----------
    if (h == 1) {
#pragma unroll
        for (int o = 0; o < 16; ++o) t16p[a][o] = t16a[o];
    }
    block_red2(cs1, cs2, red, bc, tid);        // syncs also publish t16p
    const float NC = 12.f * 512.f * 64.f;      // 393216
    float mcat = cs1 / NC;
    float rcat = rsqrtf(cs2 / NC - mcat * mcat + EPS_LN);

    // t16 values for this row (h=0 threads own the tail); LN over [16, A]
    float tv[16];
    float p1 = 0.f, p2 = 0.f;
    if (h == 0) {
#pragma unroll
        for (int o = 0; o < 16; ++o) {
            float tot = t16a[o] + t16p[a][o];
            float v = rcat * (tot - mcat * Klds[o]);
            tv[o] = v; p1 += v; p2 = fmaf(v, v, p2);
        }
    }
    block_red2(p1, p2, red, bc, tid);
    const float N16 = 16.f * 512.f;            // 8192
    float m16 = p1 / N16;
    float r16 = rsqrtf(p2 / N16 - m16 * m16 + EPS_LN);

    // c3w over 17 channels (16 normalized + raw w), then LN over A
    float v = 0.f, f1 = 0.f, f2 = 0.f;
    if (h == 0) {
        v = wIn[(size_t)b * 512 + a] * c3w[16];
#pragma unroll
        for (int o = 0; o < 16; ++o) v = fmaf((tv[o] - m16) * r16, c3w[o], v);
        f1 = v; f2 = v * v;
    }
    block_red2(f1, f2, red, bc, tid);
    float mA = f1 / 512.f;
    float rA = rsqrtf(f2 / 512.f - mA * mA + EPS_LN);
    if (h == 0) out[(size_t)b * 512 + a] = (v - mA) * rA;
}

extern "C" void kernel_launch(void* const* d_in, const int* in_sizes, int n_in,
                              void* d_out, int out_size, void* d_ws, size_t ws_size,
                              hipStream_t stream) {
    const float* s   = (const float*)d_in[0];
    const float* w   = (const float*)d_in[1];
    const float* w1d = (const float*)d_in[2];
    const float* w1p = (const float*)d_in[3];
    const float* w2d = (const float*)d_in[4];
    const float* w2p = (const float*)d_in[5];
    const float* w3d = (const float*)d_in[6];
    const float* w3p = (const float*)d_in[7];
    const float* cw  = (const float*)d_in[8];
    const float* c2w = (const float*)d_in[9];
    const float* c3w = (const float*)d_in[10];
    tcn_fused<<<dim3(256), dim3(1024), 0, stream>>>(
        s, w, w1d, w1p, w2d, w2p, w3d, w3p, cw, c2w, c3w,
        (float*)d_out, (f4*)d_ws);
}